// Round 10
// baseline (4600.510 us; speedup 1.0000x reference)
//
#include <hip/hip_runtime.h>

#define FPS_N 32768
#define FPS_M 2048
#define FPS_B 16
#define BLK_PER_B 8
#define FPS_T 576                 // 9 waves: wave 0 = comm, waves 1-8 = scan
#define SCT 512                   // scan threads
#define PTS (FPS_N / BLK_PER_B)   // 4096 points per block
#define PPT (PTS / SCT)           // 8 points per scan thread

typedef unsigned long long ull;

// FPS split 8 ways per batch, cooperative launch, wave-specialized (round 9:
// 4.34 ms). Round-10 changes, both on the measured critical path:
//  (1) COORDS RIDE THE PAYLOAD: each block publishes 4 self-validating
//      relaxed agent-scope words (line-major, 4 lines x 8 slots per parity):
//        wd = dist<<32 | (32767-gidx)<<17 | tag     (u64-max == np.argmax)
//        wx/wy/wz = coord_bits<<12 | tag
//      Comm wave polls 32 lanes (lane l -> word l>>3 of slot l&7). After
//      catch, jw = gidx>>12 and coords arrive via 3 shfls -- the post-catch
//      L2 coord fetch + broadcast (~450 cyc) disappears. Round 7's payload
//      without round 7's mistake (ONE polling wave, not nine).
//  (2) STAGGERED DOUBLE-SLOT POLL: two alternating in-flight poll loads,
//      phase-offset once by s_sleep(5) (~320 cyc) -> LLC sampling interval
//      ~RT/2 instead of ~RT -> catch delay drops ~300-500 cyc.
// Tag safety: tags monotone 1..2047 (12 bits); ws 0xAA poison -> tag field
// 0xAAA=2730 never matches; LDS part[] zero-init; LLC parity double-buffer
// (slot reuse at s+2 is provably post-consumption). Single LDS winner writer
// (comm lane 0) -> no multi-writer races.
// Numerics bit-exact vs numpy: contract off, (dx*dx+dy*dy)+dz*dz, no fma,
// strict > / lowest-global-index ties (inverted index in packed word).
__global__ __launch_bounds__(FPS_T) void fps_kernel(const float* __restrict__ pts,
                                                    float* __restrict__ out,
                                                    ull* __restrict__ ws) {
#pragma clang fp contract(off)
    __shared__ float4 sc[PTS];          // 64 KiB coords
    __shared__ ull part[8];             // tagged per-scan-wave partials
    __shared__ float swx, swy, swz;     // winner coords
    __shared__ unsigned swtag;          // winner tag (release/acquire)

    const int blk = blockIdx.x;
    const int b = blk & 15;             // batch; same-batch blocks share XCD
    const int j = blk >> 4;             // block-within-batch 0..7
    const int tid = threadIdx.x;
    const float* __restrict__ X = pts + (size_t)b * 3 * FPS_N;
    const float* __restrict__ Y = X + FPS_N;
    const float* __restrict__ Z = Y + FPS_N;
    const int off = j * PTS;
    float* __restrict__ outb = out + (size_t)b * 3 * FPS_M;
    ull* __restrict__ wsb = ws + (size_t)b * 64;  // 2 par x 4 lines x 8 slots

    for (int q = tid; q < PTS; q += FPS_T)        // one-time coord stage
        sc[q] = make_float4(X[off + q], Y[off + q], Z[off + q], 0.0f);
    if (tid < 8) part[tid] = 0;                   // kill stale-tag aliasing
    if (tid == 8) swtag = 0;
    __syncthreads();                              // only barrier (pre-loop)

    if (tid < 64) {
        // ================= comm wave =================
        const int lane = tid;
        if (j == 0 && lane == 0) {                // selection 0 = point 0
            outb[0]         = X[0];
            outb[FPS_M]     = Y[0];
            outb[2 * FPS_M] = Z[0];
        }
        for (int s = 1; s < FPS_M; ++s) {
            const unsigned tag = (unsigned)s;
            // ---- gather 8 tagged partials from LDS (trickle-in) ----
            ull pv = 0;
            bool ok = (lane >= 8);
            for (int it = 0; it < (1 << 25); ++it) {
                if (!ok) {
                    pv = __hip_atomic_load(&part[lane], __ATOMIC_RELAXED,
                                           __HIP_MEMORY_SCOPE_WORKGROUP);
                    ok = ((unsigned)(pv & 0xFFFull) == tag);
                }
                if (__all(ok)) break;
            }
            ull v = (lane < 8) ? pv : 0;
#pragma unroll
            for (int o = 4; o > 0; o >>= 1) {     // block-best in lane 0
                ull ov = __shfl_down(v, o);
                if (ov > v) v = ov;
            }
            ull* grp = wsb + (s & 1) * 32;        // parity line group (256 B)
            if (lane == 0) {
                // block-best coords from OWN LDS (no global fetch)
                const unsigned gidx = 32767u - (unsigned)((v >> 17) & 0x7FFFull);
                float4 c = sc[gidx - off];
                // 4 relaxed stores, all in flight concurrently
                __hip_atomic_store(grp + 0 * 8 + j, v,
                                   __ATOMIC_RELAXED, __HIP_MEMORY_SCOPE_AGENT);
                __hip_atomic_store(grp + 1 * 8 + j,
                                   ((ull)__float_as_uint(c.x) << 12) | tag,
                                   __ATOMIC_RELAXED, __HIP_MEMORY_SCOPE_AGENT);
                __hip_atomic_store(grp + 2 * 8 + j,
                                   ((ull)__float_as_uint(c.y) << 12) | tag,
                                   __ATOMIC_RELAXED, __HIP_MEMORY_SCOPE_AGENT);
                __hip_atomic_store(grp + 3 * 8 + j,
                                   ((ull)__float_as_uint(c.z) << 12) | tag,
                                   __ATOMIC_RELAXED, __HIP_MEMORY_SCOPE_AGENT);
            }
            // ---- staggered double-slot poll: 32 lanes, one word each ----
            ull* pa = grp + lane;                 // lane<32: contiguous 256 B
            ok = (lane >= 32);
            ull val = 0;
            ull vA = ok ? 0 : __hip_atomic_load(pa, __ATOMIC_RELAXED,
                                                __HIP_MEMORY_SCOPE_AGENT);
            __builtin_amdgcn_s_sleep(5);          // ~320 cyc phase offset
            ull vB = ok ? 0 : __hip_atomic_load(pa, __ATOMIC_RELAXED,
                                                __HIP_MEMORY_SCOPE_AGENT);
            for (int it = 0; it < (1 << 24); ++it) {
                if (!ok && ((unsigned)(vA & 0xFFFull) == tag)) { val = vA; ok = true; }
                if (__all(ok)) break;
                if (!ok) vA = __hip_atomic_load(pa, __ATOMIC_RELAXED,
                                                __HIP_MEMORY_SCOPE_AGENT);
                if (!ok && ((unsigned)(vB & 0xFFFull) == tag)) { val = vB; ok = true; }
                if (__all(ok)) break;
                if (!ok) vB = __hip_atomic_load(pa, __ATOMIC_RELAXED,
                                                __HIP_MEMORY_SCOPE_AGENT);
            }
            // ---- winner: u64-max over wd words (lanes 0-7) ----
            ull r = (lane < 8) ? val : 0;
#pragma unroll
            for (int o = 4; o > 0; o >>= 1) {
                ull orr = __shfl_down(r, o);
                if (orr > r) r = orr;
            }
            r = __shfl(r, 0);
            const int jw = (32767 - (int)((r >> 17) & 0x7FFFull)) >> 12;
            ull vx = __shfl(val, 8 + jw);         // coords from payload lanes
            ull vy = __shfl(val, 16 + jw);
            ull vz = __shfl(val, 24 + jw);
            const float px = __uint_as_float((unsigned)(vx >> 12));
            const float py = __uint_as_float((unsigned)(vy >> 12));
            const float pz = __uint_as_float((unsigned)(vz >> 12));
            if (lane == 0) {
                swx = px; swy = py; swz = pz;     // then release the tag
                __hip_atomic_store(&swtag, tag, __ATOMIC_RELEASE,
                                   __HIP_MEMORY_SCOPE_WORKGROUP);
            }
            if (j == 0 && lane == 0) {            // output row s (off scan path)
                outb[s]             = px;
                outb[FPS_M + s]     = py;
                outb[2 * FPS_M + s] = pz;
            }
        }
    } else {
        // ================= scan waves =================
        const int st = tid - 64;                  // 0..511
        const int wv = (tid >> 6) - 1;            // scan wave 0..7
        const int lane = tid & 63;
        float dist[PPT];
#pragma unroll
        for (int k = 0; k < PPT; ++k) dist[k] = 1e10f;
        float lx = X[0], ly = Y[0], lz = Z[0];    // first selection = index 0

        for (int s = 1; s < FPS_M; ++s) {
            const unsigned tag = (unsigned)s;
            float bd = -1.0f;
            int bi = 0;
#pragma unroll
            for (int k = 0; k < PPT; ++k) {
                const int q = k * SCT + st;
                float4 c = sc[q];                            // ds_read_b128
                float dx = c.x - lx, dy = c.y - ly, dz = c.z - lz;
                float d = (dx * dx + dy * dy) + dz * dz;     // numpy order
                float nd = d < dist[k] ? d : dist[k];
                dist[k] = nd;
                if (nd > bd) { bd = nd; bi = q; }            // strict >
            }
            // pack once, then 6-shfl u64-max wave reduce
            ull w = ((ull)__float_as_uint(bd) << 32)
                  | ((ull)(32767u - (unsigned)(off + bi)) << 17)
                  | (ull)tag;
#pragma unroll
            for (int o = 32; o > 0; o >>= 1) {
                ull ow = __shfl_down(w, o);
                if (ow > w) w = ow;
            }
            if (lane == 0)
                __hip_atomic_store(&part[wv], w, __ATOMIC_RELAXED,
                                   __HIP_MEMORY_SCOPE_WORKGROUP);
            // wait for winner(s): LDS broadcast spin, acquire orders coord reads
            for (int it = 0; it < (1 << 25); ++it) {
                unsigned t = __hip_atomic_load(&swtag, __ATOMIC_ACQUIRE,
                                               __HIP_MEMORY_SCOPE_WORKGROUP);
                if (t == tag) break;
            }
            lx = swx;
            ly = swy;
            lz = swz;
        }
    }
}

extern "C" void kernel_launch(void* const* d_in, const int* in_sizes, int n_in,
                              void* d_out, int out_size, void* d_ws, size_t ws_size,
                              hipStream_t stream) {
    const float* pts = (const float*)d_in[0];   // [16, 3, 32768] fp32
    float* out = (float*)d_out;                 // [16, 3, 2048] fp32
    ull* ws = (ull*)d_ws;                       // 16 batches x 64 words = 8 KB
    void* args[] = { (void*)&pts, (void*)&out, (void*)&ws };
    hipLaunchCooperativeKernel((const void*)fps_kernel,
                               dim3(FPS_B * BLK_PER_B), dim3(FPS_T),
                               args, 0, stream);
}